// Round 3
// 509.156 us; speedup vs baseline: 1.0045x; 1.0045x over previous
//
#include <hip/hip_runtime.h>
#include <math.h>

#define BATCH 64
#define HDIM  1024
#define INDIM 1024
#define NGATE 6
#define GATESZ (BATCH*HDIM)        /* 65536  */
#define PSLICE (NGATE*GATESZ)      /* 393216 */
#define KSPLIT 4

/* output layout (floats): h[65536] | C[67108864] | n[65536] | m[65536] */
#define OUT_C_OFF 65536
#define OUT_N_OFF 67174400
#define OUT_M_OFF 67239936

typedef float fx4 __attribute__((ext_vector_type(4)));

__device__ __forceinline__ float softplusf_(float z) {
    return fmaxf(z, 0.f) + log1pf(expf(-fabsf(z)));
}
__device__ __forceinline__ float sigmoidf_(float z) {
    return 1.f / (1.f + expf(-z));
}

/* ---------------- Kernel 1: fused 6-gate GEMM, split-K=4 ----------------
 * grid (192, 4), block 256.  blockIdx.x -> (gate g = x>>5, h-tile of 32).
 * Wave w (4 per block) owns 8 h rows; lane = batch index (64 lanes = 64 b).
 * W addresses are wave-uniform -> scalar loads.  x staged transposed in LDS.
 * Partials P[ks][g][b][h] in ws. */
__global__ __launch_bounds__(256) void k_gemm(
    const float* __restrict__ x,
    const float* __restrict__ Wq, const float* __restrict__ Wk,
    const float* __restrict__ Wv, const float* __restrict__ Wi,
    const float* __restrict__ Wf, const float* __restrict__ Wo,
    float* __restrict__ P)
{
    __shared__ float xt[128][65];          /* [k][b], +1 pad: conflict-free reads */
    const int tid  = threadIdx.x;
    const int lane = tid & 63;             /* = batch b */
    const int w    = __builtin_amdgcn_readfirstlane(tid >> 6);
    const int ht   = blockIdx.x;
    const int g    = ht >> 5;
    const int hb   = (ht & 31) << 5;
    const int ks   = blockIdx.y;
    const int k0   = ks << 8;              /* 256 K per split */

    const float* Wsel = (g==0)?Wq:(g==1)?Wk:(g==2)?Wv:(g==3)?Wi:(g==4)?Wf:Wo;
    const float* Wbase = Wsel + (size_t)(hb + (w<<3)) * INDIM;

    float acc[8];
#pragma unroll
    for (int j=0;j<8;j++) acc[j]=0.f;

    for (int kc = k0; kc < k0+256; kc += 128) {
        __syncthreads();
        /* stage x[0:64][kc:kc+128] -> xt[k][b] */
#pragma unroll
        for (int it=0; it<8; it++) {
            int idx = tid + (it<<8);       /* 0..2047 */
            int bb  = idx >> 5;
            int k4  = idx & 31;
            const float4 v = *(const float4*)(x + bb*INDIM + kc + (k4<<2));
            xt[(k4<<2)+0][bb] = v.x;
            xt[(k4<<2)+1][bb] = v.y;
            xt[(k4<<2)+2][bb] = v.z;
            xt[(k4<<2)+3][bb] = v.w;
        }
        __syncthreads();
        const float* Wc = Wbase + kc;
#pragma unroll 2
        for (int kb=0; kb<128; kb+=4) {
            float4 wv[8];
#pragma unroll
            for (int j=0;j<8;j++)
                wv[j] = *(const float4*)(Wc + j*INDIM + kb);
            float xv0 = xt[kb+0][lane];
            float xv1 = xt[kb+1][lane];
            float xv2 = xt[kb+2][lane];
            float xv3 = xt[kb+3][lane];
#pragma unroll
            for (int j=0;j<8;j++) {
                acc[j] = fmaf(wv[j].x, xv0, acc[j]);
                acc[j] = fmaf(wv[j].y, xv1, acc[j]);
                acc[j] = fmaf(wv[j].z, xv2, acc[j]);
                acc[j] = fmaf(wv[j].w, xv3, acc[j]);
            }
        }
    }
    float* dst = P + ((size_t)((ks*NGATE + g)*BATCH + lane))*HDIM + hb + (w<<3);
    *(float4*)(dst+0) = make_float4(acc[0],acc[1],acc[2],acc[3]);
    *(float4*)(dst+4) = make_float4(acc[4],acc[5],acc[6],acc[7]);
}

/* ------------- Kernel 1b: combine split-K + bias + activation ------------- */
__global__ __launch_bounds__(256) void k_combine(
    const float* __restrict__ P,
    const float* __restrict__ bi, const float* __restrict__ bf,
    const float* __restrict__ bo, float* __restrict__ gates)
{
    const int t = blockIdx.x*256 + threadIdx.x;   /* float4 index, 98304 total */
    const int base = t << 2;
    const int g = base >> 16;
    const int h = base & (HDIM-1);
    const float4* P4 = (const float4*)P;
    float4 z = P4[t];
#pragma unroll
    for (int s=1; s<KSPLIT; s++) {
        float4 a = P4[t + s*(PSLICE/4)];
        z.x += a.x; z.y += a.y; z.z += a.z; z.w += a.w;
    }
    if (g == 3) {
        float4 bv = *(const float4*)(bi + h);
        z.x = softplusf_(z.x + bv.x); z.y = softplusf_(z.y + bv.y);
        z.z = softplusf_(z.z + bv.z); z.w = softplusf_(z.w + bv.w);
    } else if (g == 4) {
        float4 bv = *(const float4*)(bf + h);
        z.x = sigmoidf_(z.x + bv.x); z.y = sigmoidf_(z.y + bv.y);
        z.z = sigmoidf_(z.z + bv.z); z.w = sigmoidf_(z.w + bv.w);
    } else if (g == 5) {
        float4 bv = *(const float4*)(bo + h);
        z.x = sigmoidf_(z.x + bv.x); z.y = sigmoidf_(z.y + bv.y);
        z.z = sigmoidf_(z.z + bv.z); z.w = sigmoidf_(z.w + bv.w);
    }
    ((float4*)gates)[t] = z;
}

/* ------------- Kernel 2: C update + fused C·q row dot (512 MB stream) -----
 * grid (128, 64), block 256.  b = blockIdx.y, rows r0..r0+7.
 * Wave w handles rows rA=r0+w and rB=r0+w+4; lane covers 16 cols (4 x float4).
 * v2: all 8 C-line loads (both rows) issued up front -> 2x memory-level
 * parallelism per thread; the two wave reductions run interleaved so the
 * 6-hop shuffle chains overlap. q/v fragments live in registers. */
__global__ __launch_bounds__(256) void k_update(
    const float* __restrict__ gates, const float* __restrict__ Cprev,
    float* __restrict__ Cout, float* __restrict__ hraw)
{
    const int lane = threadIdx.x & 63;
    const int w    = __builtin_amdgcn_readfirstlane((int)(threadIdx.x >> 6));
    const int b    = blockIdx.y;
    const int r0   = blockIdx.x << 3;
    const float* Q = gates + 0*GATESZ + b*HDIM;
    const float* K = gates + 1*GATESZ + b*HDIM;
    const float* V = gates + 2*GATESZ + b*HDIM;
    const float* I = gates + 3*GATESZ + b*HDIM;
    const float* F = gates + 4*GATESZ + b*HDIM;

    const int rA = r0 + w;
    const int rB = rA + 4;
    const float fA  = F[rA];
    const float ikA = I[rA] * K[rA];
    const float fB  = F[rB];
    const float ikB = I[rB] * K[rB];
    const float* cpA = Cprev + ((size_t)b<<20) + ((size_t)rA<<10);
    const float* cpB = Cprev + ((size_t)b<<20) + ((size_t)rB<<10);
    float*       coA = Cout  + ((size_t)b<<20) + ((size_t)rA<<10);
    float*       coB = Cout  + ((size_t)b<<20) + ((size_t)rB<<10);

    fx4 qf[4], vf[4];
#pragma unroll
    for (int j=0;j<4;j++) {
        int c = j*256 + (lane<<2);
        qf[j] = *(const fx4*)(Q + c);
        vf[j] = *(const fx4*)(V + c);
    }

    /* issue all 8 streaming loads before any dependent use */
    fx4 ca[4], cb[4];
#pragma unroll
    for (int j=0;j<4;j++) {
        int c = j*256 + (lane<<2);
        ca[j] = __builtin_nontemporal_load((const fx4*)(cpA + c));
    }
#pragma unroll
    for (int j=0;j<4;j++) {
        int c = j*256 + (lane<<2);
        cb[j] = __builtin_nontemporal_load((const fx4*)(cpB + c));
    }

    float pA = 0.f, pB = 0.f;
#pragma unroll
    for (int j=0;j<4;j++) {
        int c = j*256 + (lane<<2);
        fx4 cn;
        cn.x = fmaf(fA, ca[j].x, ikA*vf[j].x);
        cn.y = fmaf(fA, ca[j].y, ikA*vf[j].y);
        cn.z = fmaf(fA, ca[j].z, ikA*vf[j].z);
        cn.w = fmaf(fA, ca[j].w, ikA*vf[j].w);
        __builtin_nontemporal_store(cn, (fx4*)(coA + c));
        pA = fmaf(cn.x, qf[j].x, pA);
        pA = fmaf(cn.y, qf[j].y, pA);
        pA = fmaf(cn.z, qf[j].z, pA);
        pA = fmaf(cn.w, qf[j].w, pA);
    }
#pragma unroll
    for (int j=0;j<4;j++) {
        int c = j*256 + (lane<<2);
        fx4 cn;
        cn.x = fmaf(fB, cb[j].x, ikB*vf[j].x);
        cn.y = fmaf(fB, cb[j].y, ikB*vf[j].y);
        cn.z = fmaf(fB, cb[j].z, ikB*vf[j].z);
        cn.w = fmaf(fB, cb[j].w, ikB*vf[j].w);
        __builtin_nontemporal_store(cn, (fx4*)(coB + c));
        pB = fmaf(cn.x, qf[j].x, pB);
        pB = fmaf(cn.y, qf[j].y, pB);
        pB = fmaf(cn.z, qf[j].z, pB);
        pB = fmaf(cn.w, qf[j].w, pB);
    }

    /* interleaved butterfly reductions: the two dependency chains overlap */
#pragma unroll
    for (int off=32; off; off>>=1) {
        pA += __shfl_xor(pA, off, 64);
        pB += __shfl_xor(pB, off, 64);
    }
    if (lane == 0) {
        hraw[b*HDIM + rA] = pA;
        hraw[b*HDIM + rB] = pB;
    }
}

/* ------------- Kernel 3: n, m, denom, GroupNorm, h -------------
 * grid 64 (one block per batch), block 256; each thread owns 4 channels. */
__global__ __launch_bounds__(256) void k_final(
    const float* __restrict__ gates, const float* __restrict__ hraw,
    const float* __restrict__ n_prev, const float* __restrict__ m_prev,
    const float* __restrict__ gn_w, const float* __restrict__ gn_b,
    float* __restrict__ out)
{
    __shared__ float red[4][2];
    const int b    = blockIdx.x;
    const int tid  = threadIdx.x;
    const int lane = tid & 63;
    const int w    = tid >> 6;
    const int h0   = tid << 2;

    const float* Q = gates + 0*GATESZ + b*HDIM;
    const float* K = gates + 1*GATESZ + b*HDIM;
    const float* I = gates + 3*GATESZ + b*HDIM;
    const float* F = gates + 4*GATESZ + b*HDIM;
    const float* O = gates + 5*GATESZ + b*HDIM;

    float4 q4  = *(const float4*)(Q + h0);
    float4 k4  = *(const float4*)(K + h0);
    float4 i4  = *(const float4*)(I + h0);
    float4 f4  = *(const float4*)(F + h0);
    float4 o4  = *(const float4*)(O + h0);
    float4 np4 = *(const float4*)(n_prev + b*HDIM + h0);
    float4 mp4 = *(const float4*)(m_prev + b*HDIM + h0);

    float4 n4;
    n4.x = fmaf(f4.x, np4.x, i4.x*k4.x);
    n4.y = fmaf(f4.y, np4.y, i4.y*k4.y);
    n4.z = fmaf(f4.z, np4.z, i4.z*k4.z);
    n4.w = fmaf(f4.w, np4.w, i4.w*k4.w);
    float4 m4;
    m4.x = fmaxf(f4.x*mp4.x, i4.x);
    m4.y = fmaxf(f4.y*mp4.y, i4.y);
    m4.z = fmaxf(f4.z*mp4.z, i4.z);
    m4.w = fmaxf(f4.w*mp4.w, i4.w);
    *(float4*)(out + OUT_N_OFF + b*HDIM + h0) = n4;
    *(float4*)(out + OUT_M_OFF + b*HDIM + h0) = m4;

    /* denom = max(sum(n*q), 1) */
    float d = n4.x*q4.x + n4.y*q4.y + n4.z*q4.z + n4.w*q4.w;
#pragma unroll
    for (int off=32; off; off>>=1) d += __shfl_xor(d, off, 64);
    if (lane == 0) red[w][0] = d;
    __syncthreads();
    float denom = fmaxf(red[0][0]+red[1][0]+red[2][0]+red[3][0], 1.0f);
    const float inv = 1.0f / denom;

    float4 hr = *(const float4*)(hraw + b*HDIM + h0);
    float4 th;
    th.x = hr.x*inv; th.y = hr.y*inv; th.z = hr.z*inv; th.w = hr.w*inv;

    float s  = th.x + th.y + th.z + th.w;
    float ss = th.x*th.x + th.y*th.y + th.z*th.z + th.w*th.w;
#pragma unroll
    for (int off=32; off; off>>=1) { s += __shfl_xor(s, off, 64); ss += __shfl_xor(ss, off, 64); }
    __syncthreads();               /* red reuse */
    if (lane == 0) { red[w][0] = s; red[w][1] = ss; }
    __syncthreads();
    float mu = (red[0][0]+red[1][0]+red[2][0]+red[3][0]) * (1.0f/HDIM);
    float ms = (red[0][1]+red[1][1]+red[2][1]+red[3][1]) * (1.0f/HDIM);
    float rstd = rsqrtf(ms - mu*mu + 1e-5f);

    float4 gw = *(const float4*)(gn_w + h0);
    float4 gb = *(const float4*)(gn_b + h0);
    float4 hv;
    hv.x = o4.x * (fmaf((th.x-mu)*rstd, gw.x, gb.x));
    hv.y = o4.y * (fmaf((th.y-mu)*rstd, gw.y, gb.y));
    hv.z = o4.z * (fmaf((th.z-mu)*rstd, gw.z, gb.z));
    hv.w = o4.w * (fmaf((th.w-mu)*rstd, gw.w, gb.w));
    *(float4*)(out + b*HDIM + h0) = hv;
}

extern "C" void kernel_launch(void* const* d_in, const int* in_sizes, int n_in,
                              void* d_out, int out_size, void* d_ws, size_t ws_size,
                              hipStream_t stream) {
    const float* x      = (const float*)d_in[0];
    const float* C_prev = (const float*)d_in[1];
    const float* n_prev = (const float*)d_in[2];
    const float* m_prev = (const float*)d_in[3];
    const float* Wq     = (const float*)d_in[4];
    const float* Wk     = (const float*)d_in[5];
    const float* Wv     = (const float*)d_in[6];
    const float* Wi     = (const float*)d_in[7];
    const float* bi     = (const float*)d_in[8];
    const float* Wf     = (const float*)d_in[9];
    const float* bf     = (const float*)d_in[10];
    const float* Wo     = (const float*)d_in[11];
    const float* bo     = (const float*)d_in[12];
    const float* gn_w   = (const float*)d_in[13];
    const float* gn_b   = (const float*)d_in[14];
    float* out = (float*)d_out;

    /* ws layout: P[4][6][64][1024] (6.29 MB) | gates[6][64][1024] (1.57 MB) | hraw[64][1024] (0.26 MB) */
    float* P     = (float*)d_ws;
    float* gates = P + (size_t)KSPLIT*PSLICE;
    float* hraw  = gates + PSLICE;

    k_gemm   <<<dim3(192, KSPLIT), 256, 0, stream>>>(x, Wq, Wk, Wv, Wi, Wf, Wo, P);
    k_combine<<<dim3(384),          256, 0, stream>>>(P, bi, bf, bo, gates);
    k_update <<<dim3(128, 64),      256, 0, stream>>>(gates, C_prev, out + OUT_C_OFF, hraw);
    k_final  <<<dim3(64),           256, 0, stream>>>(gates, hraw, n_prev, m_prev, gn_w, gn_b, out);
}